// Round 1
// baseline (216.240 us; speedup 1.0000x reference)
//
#include <hip/hip_runtime.h>
#include <hip/hip_bf16.h>

#define NROWS 8192
#define DIM   1024
#define OUTD  1024
#define NE    16
#define BM    128
#define BN    128
#define BK    32
#define MAXT  96
#define NKSTEP (DIM / BK)   // 32
#define NTILE  (OUTD / BN)  // 8

typedef short s16x8 __attribute__((ext_vector_type(8)));
typedef float f32x4 __attribute__((ext_vector_type(4)));

__device__ __forceinline__ unsigned f2bf(float f) {
  __hip_bfloat16 h = __float2bfloat16(f);
  return (unsigned)__builtin_bit_cast(unsigned short, h);
}

// ---------------- init: zero counts[16] + cursors[16] ----------------
__global__ void init_kernel(int* counts) {
  int t = threadIdx.x;
  if (t < 32) counts[t] = 0;
}

// ---------------- gate: fp32 logits, softmax, argmax ----------------
__global__ __launch_bounds__(256) void gate_kernel(
    const float* __restrict__ x, const float* __restrict__ Wg,
    float* __restrict__ gate_out, int* __restrict__ eid, float* __restrict__ wsel)
{
  __shared__ __align__(16) float wg_lds[NE * 512];  // 32 KB: half of Wg
  int t = threadIdx.x;
  int wid = t >> 6, lane = t & 63;
  int n0 = blockIdx.x * 16 + wid * 4;

  float acc[4][NE];
  #pragma unroll
  for (int r = 0; r < 4; ++r)
    #pragma unroll
    for (int e = 0; e < NE; ++e) acc[r][e] = 0.f;

  const float4* wg4 = (const float4*)Wg;
  float4* wl4 = (float4*)wg_lds;

  for (int half = 0; half < 2; ++half) {
    __syncthreads();
    for (int i = t; i < NE * 128; i += 256) {
      int e = i >> 7, c = i & 127;
      wl4[i] = wg4[e * 256 + half * 128 + c];
    }
    __syncthreads();
    #pragma unroll
    for (int r = 0; r < 4; ++r) {
      const float4* xr = (const float4*)(x + (size_t)(n0 + r) * DIM) + half * 128;
      #pragma unroll
      for (int c = 0; c < 2; ++c) {
        float4 xv = xr[lane + c * 64];
        #pragma unroll
        for (int e = 0; e < NE; ++e) {
          float4 wv = wl4[e * 128 + lane + c * 64];
          acc[r][e] += xv.x * wv.x + xv.y * wv.y + xv.z * wv.z + xv.w * wv.w;
        }
      }
    }
  }

  #pragma unroll
  for (int r = 0; r < 4; ++r) {
    int n = n0 + r;
    float p[NE];
    #pragma unroll
    for (int e = 0; e < NE; ++e) {
      float v = acc[r][e];
      #pragma unroll
      for (int off = 32; off; off >>= 1) v += __shfl_xor(v, off, 64);
      p[e] = v;
    }
    float m = p[0];
    #pragma unroll
    for (int e = 1; e < NE; ++e) m = fmaxf(m, p[e]);
    float s = 0.f;
    #pragma unroll
    for (int e = 0; e < NE; ++e) { p[e] = expf(p[e] - m); s += p[e]; }
    float inv = 1.f / s;
    #pragma unroll
    for (int e = 0; e < NE; ++e) p[e] *= inv;
    if (lane == 0) {
      float4* g4 = (float4*)(gate_out + (size_t)n * NE);
      g4[0] = make_float4(p[0], p[1], p[2], p[3]);
      g4[1] = make_float4(p[4], p[5], p[6], p[7]);
      g4[2] = make_float4(p[8], p[9], p[10], p[11]);
      g4[3] = make_float4(p[12], p[13], p[14], p[15]);
      float best = p[0]; int bi = 0;
      #pragma unroll
      for (int e = 1; e < NE; ++e) { if (p[e] > best) { best = p[e]; bi = e; } }
      eid[n] = bi; wsel[n] = best;
    }
  }
}

// ---------------- count ----------------
__global__ __launch_bounds__(256) void count_kernel(
    const int* __restrict__ eid, int* __restrict__ counts)
{
  __shared__ int h[NE];
  int t = threadIdx.x;
  if (t < NE) h[t] = 0;
  __syncthreads();
  int n = blockIdx.x * 256 + t;
  atomicAdd(&h[eid[n]], 1);
  __syncthreads();
  if (t < NE && h[t]) atomicAdd(&counts[t], h[t]);
}

// ---------------- plan: offsets + tile table ----------------
__global__ void plan_kernel(const int* __restrict__ counts,
                            int* __restrict__ offsets, int4* __restrict__ tiles)
{
  int off = 0, tcount = 0;
  for (int e = 0; e < NE; ++e) {
    offsets[e] = off;
    int c = counts[e];
    for (int m = 0; m < c; m += BM)
      tiles[tcount++] = make_int4(e, off + m, (c - m < BM) ? (c - m) : BM, 0);
    off += c;
  }
  offsets[NE] = off;
  for (; tcount < MAXT; ++tcount) tiles[tcount] = make_int4(-1, 0, 0, 0);
}

// ---------------- scatter rows by expert ----------------
__global__ __launch_bounds__(256) void scatter_kernel(
    const int* __restrict__ eid, const int* __restrict__ offsets,
    int* __restrict__ cursors, int* __restrict__ rowids)
{
  __shared__ int h[NE];
  __shared__ int base[NE];
  int t = threadIdx.x;
  if (t < NE) h[t] = 0;
  __syncthreads();
  int n = blockIdx.x * 256 + t;
  int e = eid[n];
  int local = atomicAdd(&h[e], 1);
  __syncthreads();
  if (t < NE) base[t] = h[t] ? atomicAdd(&cursors[t], h[t]) : 0;
  __syncthreads();
  rowids[offsets[e] + base[e] + local] = n;
}

// ---------------- gathered per-expert GEMM (bf16 MFMA) ----------------
__global__ __launch_bounds__(256) void moe_gemm_kernel(
    const float* __restrict__ x, const float* __restrict__ We,
    const float* __restrict__ be, const int* __restrict__ rowids,
    const float* __restrict__ wsel, const int4* __restrict__ tiles,
    float* __restrict__ out)
{
  __shared__ __align__(16) char lds[4 * 8192];   // A0 A1 | B0 B1
  __shared__ int   rows_s[BM];
  __shared__ float w_s[BM];

  int4 ti = tiles[blockIdx.x];
  int e = ti.x;
  if (e < 0) return;
  int srow = ti.y, nvalid = ti.z;
  int t = threadIdx.x;
  int lane = t & 63, wid = t >> 6;
  int wm = wid >> 1, wn = wid & 1;
  int ncol0 = blockIdx.y * BN;

  if (t < BM) {
    int valid = t < nvalid;
    int rid = valid ? rowids[srow + t] : 0;
    rows_s[t] = valid ? rid : -1;
    w_s[t] = valid ? wsel[rid] : 0.f;
  }
  __syncthreads();

  // staging geometry: thread t -> rows {t>>3 + j*32}, float cols (t&7)*4..+3
  int tr = t >> 3;
  int tcf = (t & 7) << 2;
  unsigned cg  = (unsigned)(tcf >> 3);
  unsigned sub = (unsigned)((tcf & 7) << 1);   // 0 or 8
  int ridreg[4];
  #pragma unroll
  for (int j = 0; j < 4; ++j) {
    int rv = rows_s[tr + j * 32];
    ridreg[j] = rv < 0 ? 0 : rv;
  }
  const float* Wbase = We + (size_t)e * OUTD * DIM + (size_t)ncol0 * DIM;

  auto stage = [&](int b, int k0) {
    char* Ab = lds + b * 8192;
    char* Bb = lds + 16384 + b * 8192;
    #pragma unroll
    for (int j = 0; j < 4; ++j) {
      unsigned row = (unsigned)(tr + j * 32);
      unsigned a0 = ((row * 64u + cg * 16u) ^ ((row & 7u) << 4)) + sub;
      float4 v = *(const float4*)(x + (size_t)ridreg[j] * DIM + k0 + tcf);
      unsigned p0 = f2bf(v.x) | (f2bf(v.y) << 16);
      unsigned p1 = f2bf(v.z) | (f2bf(v.w) << 16);
      *(uint2*)(Ab + a0) = make_uint2(p0, p1);
      float4 u = *(const float4*)(Wbase + (size_t)row * DIM + k0 + tcf);
      unsigned q0 = f2bf(u.x) | (f2bf(u.y) << 16);
      unsigned q1 = f2bf(u.z) | (f2bf(u.w) << 16);
      *(uint2*)(Bb + a0) = make_uint2(q0, q1);
    }
  };

  f32x4 zero = {0.f, 0.f, 0.f, 0.f};
  f32x4 acc[4][4];
  #pragma unroll
  for (int i = 0; i < 4; ++i)
    #pragma unroll
    for (int j = 0; j < 4; ++j) acc[i][j] = zero;

  stage(0, 0);

  unsigned rcg  = (unsigned)(lane >> 4);
  unsigned rl15 = (unsigned)(lane & 15);

  for (int ks = 0; ks < NKSTEP; ++ks) {
    __syncthreads();
    if (ks + 1 < NKSTEP) stage((ks + 1) & 1, (ks + 1) * BK);
    char* Ab = lds + (ks & 1) * 8192;
    char* Bb = lds + 16384 + (ks & 1) * 8192;
    s16x8 af[4], bfr[4];
    #pragma unroll
    for (int f = 0; f < 4; ++f) {
      unsigned rA = (unsigned)(wm * 64 + f * 16) + rl15;
      unsigned aA = (rA * 64u + rcg * 16u) ^ ((rA & 7u) << 4);
      af[f] = *(const s16x8*)(Ab + aA);
      unsigned rB = (unsigned)(wn * 64 + f * 16) + rl15;
      unsigned aB = (rB * 64u + rcg * 16u) ^ ((rB & 7u) << 4);
      bfr[f] = *(const s16x8*)(Bb + aB);
    }
    #pragma unroll
    for (int fm = 0; fm < 4; ++fm)
      #pragma unroll
      for (int fn = 0; fn < 4; ++fn)
        acc[fm][fn] = __builtin_amdgcn_mfma_f32_16x16x32_bf16(af[fm], bfr[fn], acc[fm][fn], 0, 0, 0);
  }

  // epilogue: out[row][col] = w * (acc + be[e][col])
  int rgrp = lane >> 4;
  #pragma unroll
  for (int fn = 0; fn < 4; ++fn) {
    int col = ncol0 + wn * 64 + fn * 16 + (lane & 15);
    float bev = be[e * OUTD + col];
    #pragma unroll
    for (int fm = 0; fm < 4; ++fm) {
      #pragma unroll
      for (int j = 0; j < 4; ++j) {
        int rl = wm * 64 + fm * 16 + rgrp * 4 + j;
        int orow = rows_s[rl];
        if (orow >= 0) {
          float w = w_s[rl];
          out[(size_t)orow * OUTD + col] = w * (acc[fm][fn][j] + bev);
        }
      }
    }
  }
}

extern "C" void kernel_launch(void* const* d_in, const int* in_sizes, int n_in,
                              void* d_out, int out_size, void* d_ws, size_t ws_size,
                              hipStream_t stream) {
  const float* x  = (const float*)d_in[0];
  const float* Wg = (const float*)d_in[1];
  const float* We = (const float*)d_in[2];
  const float* be = (const float*)d_in[3];
  float* out = (float*)d_out;
  float* gate_out = out + (size_t)NROWS * OUTD;

  char* ws = (char*)d_ws;
  int*  counts  = (int*)ws;                       // 16
  int*  cursors = counts + 16;                    // 16
  int*  offsets = counts + 32;                    // 17
  int4* tiles   = (int4*)(ws + 256);              // MAXT * 16 B
  int*  eidp    = (int*)(ws + 4096);              // N ints
  float* wselp  = (float*)(ws + 4096 + 4 * NROWS);
  int*  rowids  = (int*)(ws + 4096 + 8 * NROWS);

  hipLaunchKernelGGL(init_kernel, dim3(1), dim3(64), 0, stream, counts);
  hipLaunchKernelGGL(gate_kernel, dim3(NROWS / 16), dim3(256), 0, stream,
                     x, Wg, gate_out, eidp, wselp);
  hipLaunchKernelGGL(count_kernel, dim3(NROWS / 256), dim3(256), 0, stream, eidp, counts);
  hipLaunchKernelGGL(plan_kernel, dim3(1), dim3(1), 0, stream, counts, offsets, tiles);
  hipLaunchKernelGGL(scatter_kernel, dim3(NROWS / 256), dim3(256), 0, stream,
                     eidp, offsets, cursors, rowids);
  hipLaunchKernelGGL(moe_gemm_kernel, dim3(MAXT, NTILE), dim3(256), 0, stream,
                     x, We, be, rowids, wselp, tiles, out);
}